// Round 2
// baseline (1544.014 us; speedup 1.0000x reference)
//
#include <hip/hip_runtime.h>
#include <hip/hip_bf16.h>
#include <cstdint>

typedef __bf16 bf16;
typedef __bf16 bf16x8 __attribute__((ext_vector_type(8)));
typedef float f32x4 __attribute__((ext_vector_type(4)));
typedef float f32x8 __attribute__((ext_vector_type(8)));

constexpr int Bz = 4, T = 2048, Cdim = 2048, NH = 16, HD = 128;
constexpr int QKVC = 3 * Cdim; // 6144
constexpr float NEG_BIG = -3.0e4f;

// -------------------------------------------------- fp32 -> bf16 transpose
__global__ __launch_bounds__(256)
void transpose_cvt_k(const float* __restrict__ in, bf16* __restrict__ out,
                     int R, int Ccols) {
  __shared__ bf16 tile[32][33];
  int c0 = blockIdx.x * 32, r0 = blockIdx.y * 32;
  int tx = threadIdx.x, ty = threadIdx.y; // block (32,8)
#pragma unroll
  for (int i = 0; i < 4; ++i)
    tile[ty + i * 8][tx] = (bf16)in[(size_t)(r0 + ty + i * 8) * Ccols + c0 + tx];
  __syncthreads();
#pragma unroll
  for (int i = 0; i < 4; ++i)
    out[(size_t)(c0 + ty + i * 8) * R + r0 + tx] = tile[tx][ty + i * 8];
}

// -------------------------------------------------- GEMM C = A * BT^T
// A [M,K]: fp32 if AF32 else bf16. BT [N,K] bf16. C [M,N]: fp32 if CF32 else bf16.
template <bool AF32, bool CF32>
__global__ __launch_bounds__(256)
void gemm_bt_k(const void* __restrict__ Araw, const bf16* __restrict__ BT,
               void* __restrict__ Craw, int M, int N, int K) {
  __shared__ __align__(16) bf16 As[128 * 32];
  __shared__ __align__(16) bf16 Bs[128 * 32];

  int tid = threadIdx.x;
  int w = tid >> 6, lane = tid & 63;
  int qn = lane & 15, quad = lane >> 4;
  int wm = (w >> 1) * 64, wn = (w & 1) * 64;
  size_t row0 = (size_t)blockIdx.y * 128;
  size_t col0 = (size_t)blockIdx.x * 128;

  f32x4 zero4 = {0.f, 0.f, 0.f, 0.f};
  f32x4 acc[4][4];
#pragma unroll
  for (int i = 0; i < 4; ++i)
#pragma unroll
    for (int j = 0; j < 4; ++j) acc[i][j] = zero4;

  int r = tid >> 2;        // 0..63
  int kc = (tid & 3) << 3; // 0,8,16,24
  const float* aF = (const float*)Araw;
  const bf16* aH = (const bf16*)Araw;
  const bf16* bSrc = BT + (col0 + r) * (size_t)K + kc;

  for (int k0 = 0; k0 < K; k0 += 32) {
    __syncthreads();
    if (AF32) {
      f32x8 v0 = *(const f32x8*)(aF + (row0 + r) * (size_t)K + k0 + kc);
      f32x8 v1 = *(const f32x8*)(aF + (row0 + r + 64) * (size_t)K + k0 + kc);
      bf16x8 h0, h1;
#pragma unroll
      for (int j = 0; j < 8; ++j) { h0[j] = (bf16)v0[j]; h1[j] = (bf16)v1[j]; }
      *(bf16x8*)&As[(size_t)r * 32 + kc] = h0;
      *(bf16x8*)&As[(size_t)(r + 64) * 32 + kc] = h1;
    } else {
      *(uint4*)&As[(size_t)r * 32 + kc] =
          *(const uint4*)(aH + (row0 + r) * (size_t)K + k0 + kc);
      *(uint4*)&As[(size_t)(r + 64) * 32 + kc] =
          *(const uint4*)(aH + (row0 + r + 64) * (size_t)K + k0 + kc);
    }
    *(uint4*)&Bs[(size_t)r * 32 + kc] = *(const uint4*)(bSrc + k0);
    *(uint4*)&Bs[(size_t)(r + 64) * 32 + kc] =
        *(const uint4*)(bSrc + (size_t)64 * K + k0);
    __syncthreads();

    bf16x8 aFr[4], bFr[4];
#pragma unroll
    for (int i = 0; i < 4; ++i)
      aFr[i] = *(const bf16x8*)&As[(wm + i * 16 + qn) * 32 + quad * 8];
#pragma unroll
    for (int j = 0; j < 4; ++j)
      bFr[j] = *(const bf16x8*)&Bs[(wn + j * 16 + qn) * 32 + quad * 8];
#pragma unroll
    for (int i = 0; i < 4; ++i)
#pragma unroll
      for (int j = 0; j < 4; ++j)
        acc[i][j] = __builtin_amdgcn_mfma_f32_16x16x32_bf16(aFr[i], bFr[j], acc[i][j], 0, 0, 0);
  }

#pragma unroll
  for (int i = 0; i < 4; ++i)
#pragma unroll
    for (int j = 0; j < 4; ++j)
#pragma unroll
      for (int rr = 0; rr < 4; ++rr) {
        size_t idx = (row0 + wm + i * 16 + quad * 4 + rr) * (size_t)N +
                     col0 + wn + j * 16 + qn;
        if (CF32) ((float*)Craw)[idx] = acc[i][j][rr];
        else      ((bf16*)Craw)[idx] = (bf16)acc[i][j][rr];
      }
}

// -------------------------------------------------- flash attention
// qkv: [B, T, 3C] bf16, rows = [q|k|v], head h at col h*128 per section. y: [B,T,C] bf16.
__global__ __launch_bounds__(256)
void attn_k(const bf16* qkv, bf16* y) {
  int b = blockIdx.z, h = blockIdx.y;
  int qt0 = blockIdx.x * 64;
  int tid = threadIdx.x, w = tid >> 6, lane = tid & 63;
  int qn = lane & 15, quad = lane >> 4;
  int q0 = qt0 + w * 16;

  __shared__ __align__(16) bf16 Ks[32 * 128];   // [key][hd]
  __shared__ __align__(16) bf16 Vs[128 * 32];   // [hd][key]
  __shared__ __align__(16) bf16 Ps[4][16 * 32]; // per-wave [q][key]

  const bf16* qBase = qkv + (size_t)b * T * QKVC + (size_t)h * HD;

  bf16x8 qF[4];
  {
    const bf16* qRow = qBase + (size_t)(q0 + qn) * QKVC;
#pragma unroll
    for (int c = 0; c < 4; ++c)
      qF[c] = *(const bf16x8*)(qRow + c * 32 + quad * 8);
  }

  float m_i[4], l_i[4];
#pragma unroll
  for (int rr = 0; rr < 4; ++rr) { m_i[rr] = NEG_BIG; l_i[rr] = 0.f; }
  f32x4 zero4 = {0.f, 0.f, 0.f, 0.f};
  f32x4 o[8];
#pragma unroll
  for (int cc = 0; cc < 8; ++cc) o[cc] = zero4;

  const int nTiles = qt0 / 32 + 2;
  for (int t = 0; t < nTiles; ++t) {
    int kt0 = t * 32;
    __syncthreads();
#pragma unroll
    for (int it = 0; it < 2; ++it) {
      int idx = tid + it * 256;
      int row = idx >> 4;
      int c8 = (idx & 15) << 3;
      *(uint4*)&Ks[row * 128 + c8] =
          *(const uint4*)(qBase + Cdim + (size_t)(kt0 + row) * QKVC + c8);
      bf16x8 vv = *(const bf16x8*)(qBase + 2 * Cdim + (size_t)(kt0 + row) * QKVC + c8);
#pragma unroll
      for (int j = 0; j < 8; ++j) Vs[(c8 + j) * 32 + row] = vv[j];
    }
    __syncthreads();

    if (kt0 <= q0 + 15) {
      f32x4 s0 = zero4, s1 = zero4;
#pragma unroll
      for (int c = 0; c < 4; ++c) {
        bf16x8 k0f = *(const bf16x8*)&Ks[qn * 128 + c * 32 + quad * 8];
        bf16x8 k1f = *(const bf16x8*)&Ks[(16 + qn) * 128 + c * 32 + quad * 8];
        s0 = __builtin_amdgcn_mfma_f32_16x16x32_bf16(qF[c], k0f, s0, 0, 0, 0);
        s1 = __builtin_amdgcn_mfma_f32_16x16x32_bf16(qF[c], k1f, s1, 0, 0, 0);
      }
      const float scale = 0.088388347648318447f; // 1/sqrt(128)
      float p0[4], p1[4], alpha[4];
#pragma unroll
      for (int rr = 0; rr < 4; ++rr) {
        int qIdx = q0 + quad * 4 + rr;
        float s0v = (kt0 + qn > qIdx) ? NEG_BIG : s0[rr] * scale;
        float s1v = (kt0 + 16 + qn > qIdx) ? NEG_BIG : s1[rr] * scale;
        float v = fmaxf(s0v, s1v);
        v = fmaxf(v, __shfl_xor(v, 1));
        v = fmaxf(v, __shfl_xor(v, 2));
        v = fmaxf(v, __shfl_xor(v, 4));
        v = fmaxf(v, __shfl_xor(v, 8));
        float mn = fmaxf(m_i[rr], v);
        alpha[rr] = __expf(m_i[rr] - mn);
        m_i[rr] = mn;
        p0[rr] = __expf(s0v - mn);
        p1[rr] = __expf(s1v - mn);
        float rs = p0[rr] + p1[rr];
        rs += __shfl_xor(rs, 1);
        rs += __shfl_xor(rs, 2);
        rs += __shfl_xor(rs, 4);
        rs += __shfl_xor(rs, 8);
        l_i[rr] = l_i[rr] * alpha[rr] + rs;
      }
#pragma unroll
      for (int cc = 0; cc < 8; ++cc)
#pragma unroll
        for (int rr = 0; rr < 4; ++rr) o[cc][rr] *= alpha[rr];
#pragma unroll
      for (int rr = 0; rr < 4; ++rr) {
        Ps[w][(quad * 4 + rr) * 32 + qn]      = (bf16)p0[rr];
        Ps[w][(quad * 4 + rr) * 32 + 16 + qn] = (bf16)p1[rr];
      }
      asm volatile("s_waitcnt lgkmcnt(0)" ::: "memory");
      bf16x8 pF = *(const bf16x8*)&Ps[w][qn * 32 + quad * 8];
#pragma unroll
      for (int cc = 0; cc < 8; ++cc) {
        bf16x8 vF = *(const bf16x8*)&Vs[(cc * 16 + qn) * 32 + quad * 8];
        o[cc] = __builtin_amdgcn_mfma_f32_16x16x32_bf16(pF, vF, o[cc], 0, 0, 0);
      }
    }
  }

  float inv[4];
#pragma unroll
  for (int rr = 0; rr < 4; ++rr) inv[rr] = 1.f / fmaxf(l_i[rr], 1e-30f);
  bf16* yBase = y + (size_t)b * T * Cdim + (size_t)h * HD;
#pragma unroll
  for (int cc = 0; cc < 8; ++cc)
#pragma unroll
    for (int rr = 0; rr < 4; ++rr)
      yBase[(size_t)(q0 + quad * 4 + rr) * Cdim + cc * 16 + qn] = (bf16)(o[cc][rr] * inv[rr]);
}

// -------------------------------------------------- launch
extern "C" void kernel_launch(void* const* d_in, const int* in_sizes, int n_in,
                              void* d_out, int out_size, void* d_ws, size_t ws_size,
                              hipStream_t stream) {
  const float* x     = (const float*)d_in[0]; // [4,2048,2048] fp32
  const float* Wqkv  = (const float*)d_in[1]; // [2048,6144]  fp32
  const float* Wproj = (const float*)d_in[2]; // [2048,2048]  fp32
  float* out = (float*)d_out;                 // [4,2048,2048] fp32

  char* ws = (char*)d_ws;
  // [0,96M): qkv bf16. [96M,120M): WqkvT bf16 (dead after gemm1) then y bf16
  // overlaps [96M,128M). [128M,136M): WprojT bf16. Total 136 MiB.
  bf16* qkv    = (bf16*)(ws);
  bf16* WqkvT  = (bf16*)(ws + (size_t)Bz * T * QKVC * 2);                  // @96M
  bf16* y      = WqkvT;                                                    // alias (sequenced)
  bf16* WprojT = (bf16*)(ws + (size_t)Bz * T * QKVC * 2 + (size_t)Bz * T * Cdim * 2); // @128M

  // W^T + fp32->bf16 conversion
  transpose_cvt_k<<<dim3(QKVC / 32, Cdim / 32), dim3(32, 8), 0, stream>>>(
      Wqkv, WqkvT, Cdim, QKVC);
  transpose_cvt_k<<<dim3(Cdim / 32, Cdim / 32), dim3(32, 8), 0, stream>>>(
      Wproj, WprojT, Cdim, Cdim);

  // qkv = x @ Wqkv   (A fp32, C bf16)
  gemm_bt_k<true, false><<<dim3(QKVC / 128, (Bz * T) / 128), 256, 0, stream>>>(
      (const void*)x, WqkvT, (void*)qkv, Bz * T, QKVC, Cdim);

  // y = causal attention(qkv)  (writes over WqkvT region, which is dead now)
  attn_k<<<dim3(T / 64, NH, Bz), 256, 0, stream>>>(qkv, y);

  // out = y @ Wproj  (A bf16, C fp32)
  gemm_bt_k<false, true><<<dim3(Cdim / 128, (Bz * T) / 128), 256, 0, stream>>>(
      (const void*)y, WprojT, (void*)out, Bz * T, Cdim, Cdim);
}

// Round 3
// 887.583 us; speedup vs baseline: 1.7396x; 1.7396x over previous
//
#include <hip/hip_runtime.h>
#include <hip/hip_bf16.h>
#include <cstdint>

typedef __bf16 bf16;
typedef __bf16 bf16x8 __attribute__((ext_vector_type(8)));
typedef float f32x4 __attribute__((ext_vector_type(4)));
typedef float f32x8 __attribute__((ext_vector_type(8)));

constexpr int Bz = 4, T = 2048, Cdim = 2048, NH = 16, HD = 128;
constexpr int QKVC = 3 * Cdim; // 6144
constexpr int QKC = 2 * Cdim;  // 4096 (q|k buffer row stride)
constexpr float NEG_BIG = -3.0e4f;

// -------------------------------------------------- fp32 -> bf16 transpose
__global__ __launch_bounds__(256)
void transpose_cvt_k(const float* __restrict__ in, bf16* __restrict__ out,
                     int R, int Ccols) {
  __shared__ bf16 tile[32][33];
  int c0 = blockIdx.x * 32, r0 = blockIdx.y * 32;
  int tx = threadIdx.x, ty = threadIdx.y; // block (32,8)
#pragma unroll
  for (int i = 0; i < 4; ++i)
    tile[ty + i * 8][tx] = (bf16)in[(size_t)(r0 + ty + i * 8) * Ccols + c0 + tx];
  __syncthreads();
#pragma unroll
  for (int i = 0; i < 4; ++i)
    out[(size_t)(c0 + ty + i * 8) * R + r0 + tx] = tile[tx][ty + i * 8];
}

// -------------------------------------------------- GEMM C = A * BT^T
// A [M,K]: fp32 if AF32 else bf16. BT [N,K] bf16.
// Normal cols -> Craw (fp32 if CF32 else bf16, row stride ldc).
// If SCATV: cols >= QKC scatter to Vt[b][h][d][T] (bf16).
template <bool AF32, bool CF32, bool SCATV>
__global__ __launch_bounds__(256)
void gemm_bt_k(const void* __restrict__ Araw, const bf16* __restrict__ BT,
               void* __restrict__ Craw, bf16* __restrict__ Vt,
               int M, int N, int K, int ldc) {
  __shared__ __align__(16) bf16 As[128 * 32];
  __shared__ __align__(16) bf16 Bs[128 * 32];

  int tid = threadIdx.x;
  int w = tid >> 6, lane = tid & 63;
  int qn = lane & 15, quad = lane >> 4;
  int wm = (w >> 1) * 64, wn = (w & 1) * 64;
  size_t row0 = (size_t)blockIdx.y * 128;
  size_t col0 = (size_t)blockIdx.x * 128;

  f32x4 zero4 = {0.f, 0.f, 0.f, 0.f};
  f32x4 acc[4][4];
#pragma unroll
  for (int i = 0; i < 4; ++i)
#pragma unroll
    for (int j = 0; j < 4; ++j) acc[i][j] = zero4;

  int r = tid >> 2;        // 0..63
  int kc = (tid & 3) << 3; // 0,8,16,24
  const float* aF = (const float*)Araw;
  const bf16* aH = (const bf16*)Araw;
  const bf16* bSrc = BT + (col0 + r) * (size_t)K + kc;

  for (int k0 = 0; k0 < K; k0 += 32) {
    __syncthreads();
    if (AF32) {
      f32x8 v0 = *(const f32x8*)(aF + (row0 + r) * (size_t)K + k0 + kc);
      f32x8 v1 = *(const f32x8*)(aF + (row0 + r + 64) * (size_t)K + k0 + kc);
      bf16x8 h0, h1;
#pragma unroll
      for (int j = 0; j < 8; ++j) { h0[j] = (bf16)v0[j]; h1[j] = (bf16)v1[j]; }
      *(bf16x8*)&As[(size_t)r * 32 + kc] = h0;
      *(bf16x8*)&As[(size_t)(r + 64) * 32 + kc] = h1;
    } else {
      *(uint4*)&As[(size_t)r * 32 + kc] =
          *(const uint4*)(aH + (row0 + r) * (size_t)K + k0 + kc);
      *(uint4*)&As[(size_t)(r + 64) * 32 + kc] =
          *(const uint4*)(aH + (row0 + r + 64) * (size_t)K + k0 + kc);
    }
    *(uint4*)&Bs[(size_t)r * 32 + kc] = *(const uint4*)(bSrc + k0);
    *(uint4*)&Bs[(size_t)(r + 64) * 32 + kc] =
        *(const uint4*)(bSrc + (size_t)64 * K + k0);
    __syncthreads();

    bf16x8 aFr[4], bFr[4];
#pragma unroll
    for (int i = 0; i < 4; ++i)
      aFr[i] = *(const bf16x8*)&As[(wm + i * 16 + qn) * 32 + quad * 8];
#pragma unroll
    for (int j = 0; j < 4; ++j)
      bFr[j] = *(const bf16x8*)&Bs[(wn + j * 16 + qn) * 32 + quad * 8];
#pragma unroll
    for (int i = 0; i < 4; ++i)
#pragma unroll
      for (int j = 0; j < 4; ++j)
        acc[i][j] = __builtin_amdgcn_mfma_f32_16x16x32_bf16(aFr[i], bFr[j], acc[i][j], 0, 0, 0);
  }

  if (SCATV && (int)col0 >= QKC) {
    int hh = (int)((col0 - QKC) >> 7); // whole block maps to one head
#pragma unroll
    for (int i = 0; i < 4; ++i)
#pragma unroll
      for (int j = 0; j < 4; ++j)
#pragma unroll
        for (int rr = 0; rr < 4; ++rr) {
          int row = (int)row0 + wm + i * 16 + quad * 4 + rr;
          int bb = row >> 11, tt = row & (T - 1);
          int d = wn + j * 16 + qn;
          Vt[((size_t)(bb * NH + hh) * HD + d) * T + tt] = (bf16)acc[i][j][rr];
        }
  } else {
#pragma unroll
    for (int i = 0; i < 4; ++i)
#pragma unroll
      for (int j = 0; j < 4; ++j)
#pragma unroll
        for (int rr = 0; rr < 4; ++rr) {
          size_t idx = (row0 + wm + i * 16 + quad * 4 + rr) * (size_t)ldc +
                       col0 + wn + j * 16 + qn;
          if (CF32) ((float*)Craw)[idx] = acc[i][j][rr];
          else      ((bf16*)Craw)[idx] = (bf16)acc[i][j][rr];
        }
  }
}

// -------------------------------------------------- flash attention
// qk: [B, T, 2C] bf16 (q | k). vt: [B,H,HD,T] bf16. y: [B,T,C] bf16.
// 512 threads = 8 waves; Q-tile 128 (16 rows/wave); K-tile 64.
constexpr int KSTR = 136, VSTR = 72, PSTR = 72;

__global__ __launch_bounds__(512, 4)
void attn_k(const bf16* __restrict__ qk, const bf16* __restrict__ vt,
            bf16* __restrict__ y) {
  const int b = blockIdx.z, h = blockIdx.y;
  const int qb = (int)(gridDim.x - 1 - blockIdx.x); // heavy blocks first
  const int qt0 = qb * 128;
  const int tid = threadIdx.x;
  const int w = tid >> 6, lane = tid & 63;
  const int qn = lane & 15, quad = lane >> 4;
  const int q0 = qt0 + w * 16;

  __shared__ __align__(16) bf16 Ks[64 * KSTR];       // [key][hd], padded
  __shared__ __align__(16) bf16 Vs[128 * VSTR];      // [hd][key], padded
  __shared__ __align__(16) bf16 Ps[8][16 * PSTR];    // per-wave [q][key], padded

  const bf16* qkB = qk + (size_t)b * T * QKC + h * HD;
  const bf16* vtB = vt + (size_t)(b * NH + h) * HD * T;

  bf16x8 qF[4];
  {
    const bf16* qRow = qkB + (size_t)(q0 + qn) * QKC;
#pragma unroll
    for (int c = 0; c < 4; ++c)
      qF[c] = *(const bf16x8*)(qRow + c * 32 + quad * 8);
  }

  float m_i[4], l_i[4];
#pragma unroll
  for (int rr = 0; rr < 4; ++rr) { m_i[rr] = NEG_BIG; l_i[rr] = 0.f; }
  f32x4 zero4 = {0.f, 0.f, 0.f, 0.f};
  f32x4 o[8];
#pragma unroll
  for (int cc = 0; cc < 8; ++cc) o[cc] = zero4;

  const int kr  = tid >> 4;         // 0..31
  const int kc8 = (tid & 15) << 3;  // 0..120
  const int vd  = tid >> 3;         // 0..63
  const int vk8 = (tid & 7) << 3;   // 0..56
  const float scale = 0.088388347648318447f; // 1/sqrt(128)

  const int nT = 2 * qb + 2;
  for (int t = 0; t < nT; ++t) {
    const int kt0 = t * 64;
    __syncthreads();
    {
      const bf16* kBase = qkB + Cdim; // k section
      *(bf16x8*)&Ks[kr * KSTR + kc8] =
          *(const bf16x8*)(kBase + (size_t)(kt0 + kr) * QKC + kc8);
      *(bf16x8*)&Ks[(kr + 32) * KSTR + kc8] =
          *(const bf16x8*)(kBase + (size_t)(kt0 + kr + 32) * QKC + kc8);
      *(bf16x8*)&Vs[vd * VSTR + vk8] =
          *(const bf16x8*)(vtB + (size_t)vd * T + kt0 + vk8);
      *(bf16x8*)&Vs[(vd + 64) * VSTR + vk8] =
          *(const bf16x8*)(vtB + (size_t)(vd + 64) * T + kt0 + vk8);
    }
    __syncthreads();

    if (kt0 > q0 + 15) continue; // wave-uniform; barriers already passed

    // ---- S = Q K^T : s[ksub][rr] = S[q0+quad*4+rr][kt0+ksub*16+qn]
    f32x4 s[4] = {zero4, zero4, zero4, zero4};
#pragma unroll
    for (int c = 0; c < 4; ++c)
#pragma unroll
      for (int ks = 0; ks < 4; ++ks) {
        bf16x8 kf = *(const bf16x8*)&Ks[(ks * 16 + qn) * KSTR + c * 32 + quad * 8];
        s[ks] = __builtin_amdgcn_mfma_f32_16x16x32_bf16(qF[c], kf, s[ks], 0, 0, 0);
      }

    const bool maskT = (kt0 + 63 > q0);
    float p[4][4];
#pragma unroll
    for (int rr = 0; rr < 4; ++rr) {
      const int qIdx = q0 + quad * 4 + rr;
      float sv[4];
#pragma unroll
      for (int ks = 0; ks < 4; ++ks) {
        sv[ks] = s[ks][rr] * scale;
        if (maskT && (kt0 + ks * 16 + qn > qIdx)) sv[ks] = NEG_BIG;
      }
      float mx = fmaxf(fmaxf(sv[0], sv[1]), fmaxf(sv[2], sv[3]));
      mx = fmaxf(mx, __shfl_xor(mx, 1));
      mx = fmaxf(mx, __shfl_xor(mx, 2));
      mx = fmaxf(mx, __shfl_xor(mx, 4));
      mx = fmaxf(mx, __shfl_xor(mx, 8));
      float mn = fmaxf(m_i[rr], mx);
      float alpha = __expf(m_i[rr] - mn);
      m_i[rr] = mn;
      float rs = 0.f;
#pragma unroll
      for (int ks = 0; ks < 4; ++ks) {
        float pv = __expf(sv[ks] - mn);
        p[ks][rr] = pv;
        rs += pv;
      }
      rs += __shfl_xor(rs, 1);
      rs += __shfl_xor(rs, 2);
      rs += __shfl_xor(rs, 4);
      rs += __shfl_xor(rs, 8);
      l_i[rr] = l_i[rr] * alpha + rs;
#pragma unroll
      for (int cc = 0; cc < 8; ++cc) o[cc][rr] *= alpha;
    }

    // ---- P: C-layout regs -> per-wave LDS -> A-layout frags
    bf16* Pw = &Ps[w][0];
#pragma unroll
    for (int ks = 0; ks < 4; ++ks)
#pragma unroll
      for (int rr = 0; rr < 4; ++rr)
        Pw[(quad * 4 + rr) * PSTR + ks * 16 + qn] = (bf16)p[ks][rr];
    asm volatile("s_waitcnt lgkmcnt(0)" ::: "memory");

#pragma unroll
    for (int k32 = 0; k32 < 2; ++k32) {
      bf16x8 pF = *(const bf16x8*)&Pw[qn * PSTR + k32 * 32 + quad * 8];
#pragma unroll
      for (int cc = 0; cc < 8; ++cc) {
        bf16x8 vf = *(const bf16x8*)&Vs[(cc * 16 + qn) * VSTR + k32 * 32 + quad * 8];
        o[cc] = __builtin_amdgcn_mfma_f32_16x16x32_bf16(pF, vf, o[cc], 0, 0, 0);
      }
    }
  }

  float inv[4];
#pragma unroll
  for (int rr = 0; rr < 4; ++rr) inv[rr] = 1.f / fmaxf(l_i[rr], 1e-30f);
  bf16* yB = y + (size_t)b * T * Cdim + h * HD;
#pragma unroll
  for (int cc = 0; cc < 8; ++cc)
#pragma unroll
    for (int rr = 0; rr < 4; ++rr)
      yB[(size_t)(q0 + quad * 4 + rr) * Cdim + cc * 16 + qn] =
          (bf16)(o[cc][rr] * inv[rr]);
}

// -------------------------------------------------- launch
extern "C" void kernel_launch(void* const* d_in, const int* in_sizes, int n_in,
                              void* d_out, int out_size, void* d_ws, size_t ws_size,
                              hipStream_t stream) {
  const float* x     = (const float*)d_in[0]; // [4,2048,2048] fp32
  const float* Wqkv  = (const float*)d_in[1]; // [2048,6144]  fp32
  const float* Wproj = (const float*)d_in[2]; // [2048,2048]  fp32
  float* out = (float*)d_out;                 // [4,2048,2048] fp32

  char* ws = (char*)d_ws;
  // [0,64M): qk bf16 [B,T,2C]. [64M,96M): Vt bf16 [B,H,HD,T].
  // [96M,120M): WqkvT (dead after gemm1); y bf16 [B,T,C] aliases [96M,128M).
  // [128M,136M): WprojT. Total 136 MiB (same as proven round-2 footprint).
  bf16* qkbuf  = (bf16*)(ws);
  bf16* Vt     = (bf16*)(ws + (size_t)64 * 1024 * 1024);
  bf16* WqkvT  = (bf16*)(ws + (size_t)96 * 1024 * 1024);
  bf16* y      = WqkvT; // alias, sequenced
  bf16* WprojT = (bf16*)(ws + (size_t)128 * 1024 * 1024);

  transpose_cvt_k<<<dim3(QKVC / 32, Cdim / 32), dim3(32, 8), 0, stream>>>(
      Wqkv, WqkvT, Cdim, QKVC);
  transpose_cvt_k<<<dim3(Cdim / 32, Cdim / 32), dim3(32, 8), 0, stream>>>(
      Wproj, WprojT, Cdim, Cdim);

  // qkv GEMM: q,k -> qkbuf; v -> Vt (scattered transposed)
  gemm_bt_k<true, false, true><<<dim3(QKVC / 128, (Bz * T) / 128), 256, 0, stream>>>(
      (const void*)x, WqkvT, (void*)qkbuf, Vt, Bz * T, QKVC, Cdim, QKC);

  // causal flash attention
  attn_k<<<dim3(T / 128, NH, Bz), 512, 0, stream>>>(qkbuf, Vt, y);

  // out = y @ Wproj
  gemm_bt_k<false, true, false><<<dim3(Cdim / 128, (Bz * T) / 128), 256, 0, stream>>>(
      (const void*)y, WprojT, (void*)out, nullptr, Bz * T, Cdim, Cdim, Cdim);
}

// Round 4
// 829.551 us; speedup vs baseline: 1.8613x; 1.0700x over previous
//
#include <hip/hip_runtime.h>
#include <hip/hip_bf16.h>
#include <cstdint>

typedef __bf16 bf16;
typedef __bf16 bf16x8 __attribute__((ext_vector_type(8)));
typedef float f32x4 __attribute__((ext_vector_type(4)));
typedef float f32x8 __attribute__((ext_vector_type(8)));

constexpr int Bz = 4, T = 2048, Cdim = 2048, NH = 16, HD = 128;
constexpr int QKVC = 3 * Cdim; // 6144
constexpr int QKC = 2 * Cdim;  // 4096 (q|k buffer row stride)
constexpr float NEG_BIG = -3.0e4f;

// async global->LDS, 16B per lane; l must be the WAVE-UNIFORM base
__device__ __forceinline__ void load_lds16(const bf16* g, const bf16* l) {
  __builtin_amdgcn_global_load_lds(
      (const __attribute__((address_space(1))) void*)g,
      (__attribute__((address_space(3))) void*)l, 16, 0, 0);
}

// -------------------------------------------------- fp32 -> bf16 convert
__global__ __launch_bounds__(256)
void cvt_bf16_k(const float* __restrict__ in, bf16* __restrict__ out) {
  size_t i = (size_t)blockIdx.x * 256 + threadIdx.x;
  f32x8 v = *(const f32x8*)(in + i * 8);
  bf16x8 h;
#pragma unroll
  for (int j = 0; j < 8; ++j) h[j] = (bf16)v[j];
  *(bf16x8*)(out + i * 8) = h;
}

// -------------------------------------------------- fp32 -> bf16 transpose
__global__ __launch_bounds__(256)
void transpose_cvt_k(const float* __restrict__ in, bf16* __restrict__ out,
                     int R, int Ccols) {
  __shared__ bf16 tile[32][33];
  int c0 = blockIdx.x * 32, r0 = blockIdx.y * 32;
  int tx = threadIdx.x, ty = threadIdx.y; // block (32,8)
#pragma unroll
  for (int i = 0; i < 4; ++i)
    tile[ty + i * 8][tx] = (bf16)in[(size_t)(r0 + ty + i * 8) * Ccols + c0 + tx];
  __syncthreads();
#pragma unroll
  for (int i = 0; i < 4; ++i)
    out[(size_t)(c0 + ty + i * 8) * R + r0 + tx] = tile[tx][ty + i * 8];
}

// -------------------------------------------------- GEMM C = A * BT^T
// A [M,K] bf16, BT [N,K] bf16. Staging via global_load_lds (16B/lane).
// Normal cols -> Craw (fp32 if CF32 else bf16, row stride ldc).
// If SCATV: cols >= QKC scatter to Vt[b][h][d][T] (bf16).
template <bool CF32, bool SCATV>
__global__ __launch_bounds__(256)
void gemm_bt_k(const bf16* __restrict__ A, const bf16* __restrict__ BT,
               void* __restrict__ Craw, bf16* __restrict__ Vt,
               int M, int N, int K, int ldc) {
  __shared__ __align__(16) bf16 As[128 * 32];
  __shared__ __align__(16) bf16 Bs[128 * 32];

  int tid = threadIdx.x;
  int w = tid >> 6, lane = tid & 63;
  int qn = lane & 15, quad = lane >> 4;
  int wm = (w >> 1) * 64, wn = (w & 1) * 64;
  size_t row0 = (size_t)blockIdx.y * 128;
  size_t col0 = (size_t)blockIdx.x * 128;

  f32x4 zero4 = {0.f, 0.f, 0.f, 0.f};
  f32x4 acc[4][4];
#pragma unroll
  for (int i = 0; i < 4; ++i)
#pragma unroll
    for (int j = 0; j < 4; ++j) acc[i][j] = zero4;

  // staging: wave w stages 16-row chunks {2w, 2w+1} of both tiles.
  // lane -> (row=lane>>2, 8-elem col chunk=(lane&3)*8): LDS offset == lane*16B. 
  int r16 = lane >> 2;
  int kcl = (lane & 3) << 3;
  const bf16* aBase = A + (row0 + w * 32 + r16) * (size_t)K + kcl;
  const bf16* bBase = BT + (col0 + w * 32 + r16) * (size_t)K + kcl;
  const bf16* aU0 = &As[(w * 2) * 512];
  const bf16* aU1 = &As[(w * 2 + 1) * 512];
  const bf16* bU0 = &Bs[(w * 2) * 512];
  const bf16* bU1 = &Bs[(w * 2 + 1) * 512];

  for (int k0 = 0; k0 < K; k0 += 32) {
    __syncthreads();
    load_lds16(aBase + k0, aU0);
    load_lds16(aBase + (size_t)16 * K + k0, aU1);
    load_lds16(bBase + k0, bU0);
    load_lds16(bBase + (size_t)16 * K + k0, bU1);
    __syncthreads();

    bf16x8 aFr[4], bFr[4];
#pragma unroll
    for (int i = 0; i < 4; ++i)
      aFr[i] = *(const bf16x8*)&As[(wm + i * 16 + qn) * 32 + quad * 8];
#pragma unroll
    for (int j = 0; j < 4; ++j)
      bFr[j] = *(const bf16x8*)&Bs[(wn + j * 16 + qn) * 32 + quad * 8];
#pragma unroll
    for (int i = 0; i < 4; ++i)
#pragma unroll
      for (int j = 0; j < 4; ++j)
        acc[i][j] = __builtin_amdgcn_mfma_f32_16x16x32_bf16(aFr[i], bFr[j], acc[i][j], 0, 0, 0);
  }

  if (SCATV && (int)col0 >= QKC) {
    int hh = (int)((col0 - QKC) >> 7); // whole block maps to one head
#pragma unroll
    for (int i = 0; i < 4; ++i)
#pragma unroll
      for (int j = 0; j < 4; ++j)
#pragma unroll
        for (int rr = 0; rr < 4; ++rr) {
          int row = (int)row0 + wm + i * 16 + quad * 4 + rr;
          int bb = row >> 11, tt = row & (T - 1);
          int d = wn + j * 16 + qn;
          Vt[((size_t)(bb * NH + hh) * HD + d) * T + tt] = (bf16)acc[i][j][rr];
        }
  } else {
#pragma unroll
    for (int i = 0; i < 4; ++i)
#pragma unroll
      for (int j = 0; j < 4; ++j)
#pragma unroll
        for (int rr = 0; rr < 4; ++rr) {
          size_t idx = (row0 + wm + i * 16 + quad * 4 + rr) * (size_t)ldc +
                       col0 + wn + j * 16 + qn;
          if (CF32) ((float*)Craw)[idx] = acc[i][j][rr];
          else      ((bf16*)Craw)[idx] = (bf16)acc[i][j][rr];
        }
  }
}

// -------------------------------------------------- flash attention
// qk: [B, T, 2C] bf16 (q | k). vt: [B,H,HD,T] bf16. y: [B,T,C] bf16.
// 512 threads = 8 waves; Q-tile 128 (16 rows/wave); K-tile 64.
constexpr int KSTR = 136, VSTR = 72, PSTR = 72;

__global__ __launch_bounds__(512, 4)
void attn_k(const bf16* __restrict__ qk, const bf16* __restrict__ vt,
            bf16* __restrict__ y) {
  const int b = blockIdx.z, h = blockIdx.y;
  const int qb = (int)(gridDim.x - 1 - blockIdx.x); // heavy blocks first
  const int qt0 = qb * 128;
  const int tid = threadIdx.x;
  const int w = tid >> 6, lane = tid & 63;
  const int qn = lane & 15, quad = lane >> 4;
  const int q0 = qt0 + w * 16;

  __shared__ __align__(16) bf16 Ks[64 * KSTR];    // [key][hd], padded
  __shared__ __align__(16) bf16 Vs[128 * VSTR];   // [hd][key], padded
  __shared__ __align__(16) bf16 Ps[8][16 * PSTR]; // per-wave [q][key], padded

  const bf16* qkB = qk + (size_t)b * T * QKC + h * HD;
  const bf16* vtB = vt + (size_t)(b * NH + h) * HD * T;

  bf16x8 qF[4];
  {
    const bf16* qRow = qkB + (size_t)(q0 + qn) * QKC;
#pragma unroll
    for (int c = 0; c < 4; ++c)
      qF[c] = *(const bf16x8*)(qRow + c * 32 + quad * 8);
  }

  float m_i[4], l_i[4];
#pragma unroll
  for (int rr = 0; rr < 4; ++rr) { m_i[rr] = NEG_BIG; l_i[rr] = 0.f; }
  f32x4 zero4 = {0.f, 0.f, 0.f, 0.f};
  f32x4 o[8];
#pragma unroll
  for (int cc = 0; cc < 8; ++cc) o[cc] = zero4;

  const int kr  = tid >> 4;        // 0..31
  const int kc8 = (tid & 15) << 3; // 0..120
  const int vd  = tid >> 3;        // 0..63
  const int vk8 = (tid & 7) << 3;  // 0..56
  const float scale = 0.088388347648318447f; // 1/sqrt(128)

  const int nT = 2 * qb + 2;
  for (int t = 0; t < nT; ++t) {
    const int kt0 = t * 64;
    __syncthreads();
    {
      const bf16* kBase = qkB + Cdim; // k section
      *(bf16x8*)&Ks[kr * KSTR + kc8] =
          *(const bf16x8*)(kBase + (size_t)(kt0 + kr) * QKC + kc8);
      *(bf16x8*)&Ks[(kr + 32) * KSTR + kc8] =
          *(const bf16x8*)(kBase + (size_t)(kt0 + kr + 32) * QKC + kc8);
      *(bf16x8*)&Vs[vd * VSTR + vk8] =
          *(const bf16x8*)(vtB + (size_t)vd * T + kt0 + vk8);
      *(bf16x8*)&Vs[(vd + 64) * VSTR + vk8] =
          *(const bf16x8*)(vtB + (size_t)(vd + 64) * T + kt0 + vk8);
    }
    __syncthreads();

    if (kt0 > q0 + 15) continue; // wave-uniform; barriers already passed

    // ---- S = Q K^T : s[ksub][rr] = S[q0+quad*4+rr][kt0+ksub*16+qn]
    f32x4 s[4] = {zero4, zero4, zero4, zero4};
#pragma unroll
    for (int c = 0; c < 4; ++c)
#pragma unroll
      for (int ks = 0; ks < 4; ++ks) {
        bf16x8 kf = *(const bf16x8*)&Ks[(ks * 16 + qn) * KSTR + c * 32 + quad * 8];
        s[ks] = __builtin_amdgcn_mfma_f32_16x16x32_bf16(qF[c], kf, s[ks], 0, 0, 0);
      }

    const bool maskT = (kt0 + 63 > q0);
    float p[4][4];
#pragma unroll
    for (int rr = 0; rr < 4; ++rr) {
      const int qIdx = q0 + quad * 4 + rr;
      float sv[4];
#pragma unroll
      for (int ks = 0; ks < 4; ++ks) {
        sv[ks] = s[ks][rr] * scale;
        if (maskT && (kt0 + ks * 16 + qn > qIdx)) sv[ks] = NEG_BIG;
      }
      float mx = fmaxf(fmaxf(sv[0], sv[1]), fmaxf(sv[2], sv[3]));
      mx = fmaxf(mx, __shfl_xor(mx, 1));
      mx = fmaxf(mx, __shfl_xor(mx, 2));
      mx = fmaxf(mx, __shfl_xor(mx, 4));
      mx = fmaxf(mx, __shfl_xor(mx, 8));
      float mn = fmaxf(m_i[rr], mx);
      float alpha = __expf(m_i[rr] - mn);
      m_i[rr] = mn;
      float rs = 0.f;
#pragma unroll
      for (int ks = 0; ks < 4; ++ks) {
        float pv = __expf(sv[ks] - mn);
        p[ks][rr] = pv;
        rs += pv;
      }
      rs += __shfl_xor(rs, 1);
      rs += __shfl_xor(rs, 2);
      rs += __shfl_xor(rs, 4);
      rs += __shfl_xor(rs, 8);
      l_i[rr] = l_i[rr] * alpha + rs;
#pragma unroll
      for (int cc = 0; cc < 8; ++cc) o[cc][rr] *= alpha;
    }

    // ---- P: C-layout regs -> per-wave LDS -> A-layout frags
    bf16* Pw = &Ps[w][0];
#pragma unroll
    for (int ks = 0; ks < 4; ++ks)
#pragma unroll
      for (int rr = 0; rr < 4; ++rr)
        Pw[(quad * 4 + rr) * PSTR + ks * 16 + qn] = (bf16)p[ks][rr];
    asm volatile("s_waitcnt lgkmcnt(0)" ::: "memory");

#pragma unroll
    for (int k32 = 0; k32 < 2; ++k32) {
      bf16x8 pF = *(const bf16x8*)&Pw[qn * PSTR + k32 * 32 + quad * 8];
#pragma unroll
      for (int cc = 0; cc < 8; ++cc) {
        bf16x8 vf = *(const bf16x8*)&Vs[(cc * 16 + qn) * VSTR + k32 * 32 + quad * 8];
        o[cc] = __builtin_amdgcn_mfma_f32_16x16x32_bf16(pF, vf, o[cc], 0, 0, 0);
      }
    }
  }

  float inv[4];
#pragma unroll
  for (int rr = 0; rr < 4; ++rr) inv[rr] = 1.f / fmaxf(l_i[rr], 1e-30f);
  bf16* yB = y + (size_t)b * T * Cdim + h * HD;
#pragma unroll
  for (int cc = 0; cc < 8; ++cc)
#pragma unroll
    for (int rr = 0; rr < 4; ++rr)
      yB[(size_t)(q0 + quad * 4 + rr) * Cdim + cc * 16 + qn] =
          (bf16)(o[cc][rr] * inv[rr]);
}

// -------------------------------------------------- launch
extern "C" void kernel_launch(void* const* d_in, const int* in_sizes, int n_in,
                              void* d_out, int out_size, void* d_ws, size_t ws_size,
                              hipStream_t stream) {
  const float* x     = (const float*)d_in[0]; // [4,2048,2048] fp32
  const float* Wqkv  = (const float*)d_in[1]; // [2048,6144]  fp32
  const float* Wproj = (const float*)d_in[2]; // [2048,2048]  fp32
  float* out = (float*)d_out;                 // [4,2048,2048] fp32

  char* ws = (char*)d_ws;
  // ws: [0,64M) qk bf16. [64M,96M) Vt bf16. [96M,120M) WqkvT (dead after
  // gemm1) / y bf16 aliases [96M,128M). [128M,136M) WprojT. Total 136 MiB.
  // xb (bf16 copy of x, 32MB) lives in d_out, which is dead until gemm2
  // fully overwrites it.
  bf16* qkbuf  = (bf16*)(ws);
  bf16* Vt     = (bf16*)(ws + (size_t)64 * 1024 * 1024);
  bf16* WqkvT  = (bf16*)(ws + (size_t)96 * 1024 * 1024);
  bf16* y      = WqkvT; // alias, sequenced
  bf16* WprojT = (bf16*)(ws + (size_t)128 * 1024 * 1024);
  bf16* xb     = (bf16*)d_out; // scratch until gemm2 overwrites

  cvt_bf16_k<<<dim3((Bz * T * Cdim) / (256 * 8)), 256, 0, stream>>>(x, xb);
  transpose_cvt_k<<<dim3(QKVC / 32, Cdim / 32), dim3(32, 8), 0, stream>>>(
      Wqkv, WqkvT, Cdim, QKVC);
  transpose_cvt_k<<<dim3(Cdim / 32, Cdim / 32), dim3(32, 8), 0, stream>>>(
      Wproj, WprojT, Cdim, Cdim);

  // qkv GEMM: q,k -> qkbuf; v -> Vt (scattered transposed)
  gemm_bt_k<false, true><<<dim3(QKVC / 128, (Bz * T) / 128), 256, 0, stream>>>(
      xb, WqkvT, (void*)qkbuf, Vt, Bz * T, QKVC, Cdim, QKC);

  // causal flash attention
  attn_k<<<dim3(T / 128, NH, Bz), 512, 0, stream>>>(qkbuf, Vt, y);

  // out = y @ Wproj
  gemm_bt_k<true, false><<<dim3(Cdim / 128, (Bz * T) / 128), 256, 0, stream>>>(
      y, WprojT, (void*)out, nullptr, Bz * T, Cdim, Cdim, Cdim);
}